// Round 10
// baseline (159.255 us; speedup 1.0000x reference)
//
#include <hip/hip_runtime.h>
#include <hip/hip_bf16.h>

// Conv 3x3, C_IN=128, C_OUT=256, H=W=256, pad=1, stride=1, batch=1.
// R16: FUSE the x-prepass into the conv kernel (decisive residual experiment).
//   R15 post-mortem: occupancy 17->33% with dur 55 (worse) -> wave count not the
//   lever; symmetric blocks convoy at vmcnt(0). Conv is pinned 50-57 us across 6
//   structures. The robust anomaly: total-conv ~= 80-85 us EVERY round. Top-5 always
//   conv => prep < 51 us, but may be ~40-50 of the residual (R13 fixed its write,
//   not its strided fp32 read or its existence).
//   Now: conv reads x (fp32 NCHW) directly: per kh, 4 ci-chunk passes {float4
//   interior + 2 predicated halo scalars -> cvt -> Xs[32][132] -> LDS xpose ->
//   Bs[130][128], verified 16-slot XOR}. Pad rows/cols materialized in-kernel.
//   A still gload_lds from wr (tiny 128-block weight-reorder prep remains).
//   Compute = R15's verified rotate path (B chunk = ciq*4+quad now global).
//   xb workspace (17 MB round trip) and edge-zeroing: DELETED.
//   LDS 66,304 B -> 2 blocks/CU. Predicted: WRITE exactly 67.1 MB; total ~90-100 us
//   if prep-x was the residual, else >=125 (theory dead -> single-dispatch test next).

typedef short bf16x8 __attribute__((ext_vector_type(8)));    // 8 bf16 = 4 VGPRs
typedef float f32x4 __attribute__((ext_vector_type(4)));
typedef int   i32x4 __attribute__((ext_vector_type(4)));
typedef unsigned short u16x4 __attribute__((ext_vector_type(4)));
typedef unsigned short u16x8 __attribute__((ext_vector_type(8)));

#define CIN   128
#define COUT  256
#define HH    256
#define WW    256

static __device__ __forceinline__ unsigned short f2bf(float v) {
    __hip_bfloat16 b = __float2bfloat16(v);
    return *reinterpret_cast<unsigned short*>(&b);
}

static __device__ __forceinline__ void gload_lds16(const unsigned short* g, unsigned short* l) {
    __builtin_amdgcn_global_load_lds(
        (const __attribute__((address_space(1))) unsigned int*)g,
        (__attribute__((address_space(3))) unsigned int*)l, 16, 0, 0);
}

// DPP rotate within each 16-lane row: row_ror:15 -> lane i <- lane i+1 ; ror:14 -> +2.
template<int CTRL>
static __device__ __forceinline__ bf16x8 rotf(bf16x8 a) {
    i32x4 ai = __builtin_bit_cast(i32x4, a);
    i32x4 r;
    #pragma unroll
    for (int j = 0; j < 4; ++j)
        r[j] = __builtin_amdgcn_mov_dpp(ai[j], CTRL, 0xF, 0xF, true);
    return __builtin_bit_cast(bf16x8, r);
}
#define ROR_P1 0x12F   // row_ror:15  (shift +1 lane)
#define ROR_P2 0x12E   // row_ror:14  (shift +2 lanes)

// ---------------- dispatch 1: weight reorder ONLY (x-prepass deleted) ----------------
// grid 128 x 256: one thread per (co,ci); wr[khw][co*128+ci] = bf16(w[co][ci][khw]).
__global__ __launch_bounds__(256) void prep_kernel(const float* __restrict__ w,
                                                   unsigned short* __restrict__ wr) {
    int p = blockIdx.x * 256 + threadIdx.x;    // 0..32767 = co*128+ci
    const float* src = w + p * 9;
    #pragma unroll
    for (int khw = 0; khw < 9; ++khw)
        wr[khw * (COUT * CIN) + p] = f2bf(src[khw]);
}

// ---------------- dispatch 2: fused implicit-GEMM MFMA conv --------------------------
// 1024 blocks x 256 thr (4 waves of 32co x 128sp). Block = 128co x 128sp of row h.
// Per kh: stage Bs[130 local cols][128 ci] bf16 from x directly (4 ci-chunk passes via
// Xs scratch; halo cols / out-of-range rows -> zeros). Per (kh,ciq): A planes
// [128co][32ci] x3 kw via gload_lds from wr; compute = R15 rotate path.
// Bs: 16B chunk cg (0..15) of col lc at slot cg^(lc&15). A: chunk c of row r at
// slot c^((r>>1)&3). LDS total 66304 B -> 2 blocks/CU.
__global__ __launch_bounds__(256, 2) void conv_mfma_kernel(const float* __restrict__ x,
                                                           const unsigned short* __restrict__ wr,
                                                           const float* __restrict__ bias,
                                                           float* __restrict__ out) {
    __shared__ unsigned short A0[128 * 32];    // 8192 B  (kw=0)
    __shared__ unsigned short A1[128 * 32];    // 8192 B  (kw=1)
    __shared__ unsigned short A2[128 * 32];    // 8192 B  (kw=2)
    __shared__ unsigned short Bs[130 * 128];   // 33280 B
    __shared__ unsigned short Xs[32 * 132];    // 8448 B  ; total 66304 B

    // XCD-chunked bijective swizzle: 1024 blocks, 8 XCDs -> 128 per XCD; the 4
    // quadrants (2co x 2sp) of one h are adjacent -> share x rows / wr in L2.
    int bid   = blockIdx.x;
    int inner = bid >> 3;                       // 0..127
    int h     = (bid & 7) * 32 + (inner >> 2);  // 0..255
    int co0   = (inner & 1) * 128;              // co half
    int s0    = ((inner >> 1) & 1) * 128;       // spatial half

    int t    = threadIdx.x;     // 0..255
    int lane = t & 63;
    int wave = t >> 6;          // 0..3 -> co sub-block (32 co each)
    int quad = lane >> 4;
    int l16  = lane & 15;

    f32x4 acc[2][8];
    #pragma unroll
    for (int mi = 0; mi < 2; ++mi)
        #pragma unroll
        for (int ni = 0; ni < 8; ++ni)
            acc[mi][ni] = (f32x4){0.f, 0.f, 0.f, 0.f};

    // stage A planes for (kh, ciq): 3 x 512 segs of 16B (2 segs/thread each)
    auto stageA = [&](int kh_, int ciq_) {
        const unsigned short* wbase =
            wr + (size_t)(kh_ * 3) * (COUT * CIN) + co0 * CIN + ciq_ * 32;
        #pragma unroll
        for (int it = 0; it < 2; ++it) {
            int seg = it * 256 + t;           // 0..511
            int r   = seg >> 2;
            int s   = seg & 3;
            int c   = s ^ ((r >> 1) & 3);
            const unsigned short* src = wbase + r * CIN + c * 8;
            gload_lds16(src,                    &A0[seg * 8]);
            gload_lds16(src + (COUT * CIN),     &A1[seg * 8]);
            gload_lds16(src + 2 * (COUT * CIN), &A2[seg * 8]);
        }
    };

    #pragma unroll 1
    for (int kh = 0; kh < 3; ++kh) {
        int row = h + kh - 1;                 // input row (pad space)

        // A for (kh,0): issue early -- DMA lands under the Bs fill
        stageA(kh, 0);

        if (row >= 0 && row < HH) {
            // ---- Bs fill: 4 ci-chunk passes through Xs ----
            #pragma unroll 1
            for (int cic = 0; cic < 4; ++cic) {
                // interior: gw in [s0, s0+128) -> Xs cols 0..127 (aligned float4)
                const float* xbase = x + (size_t)(cic * 32) * (HH * WW) + (size_t)row * WW + s0;
                #pragma unroll
                for (int it = 0; it < 4; ++it) {
                    int seg = it * 256 + t;    // 0..1023 = 32 ci x 32 float4
                    int ci  = seg >> 5;
                    int f4i = seg & 31;
                    float4 v = *(const float4*)(xbase + (size_t)ci * (HH * WW) + f4i * 4);
                    u16x4 pk;
                    pk.x = f2bf(v.x); pk.y = f2bf(v.y); pk.z = f2bf(v.z); pk.w = f2bf(v.w);
                    *(u16x4*)(&Xs[ci * 132 + f4i * 4]) = pk;
                }
                // halos: side0 -> gw=s0-1 -> Xs col 129 ; side1 -> gw=s0+128 -> col 128
                if (t < 64) {
                    int ci   = t >> 1;
                    int side = t & 1;
                    int gw   = s0 - 1 + side * 129;
                    float vv = (gw >= 0 && gw < WW)
                        ? x[(size_t)(cic * 32 + ci) * (HH * WW) + (size_t)row * WW + gw] : 0.f;
                    Xs[ci * 132 + 129 - side] = f2bf(vv);
                }
                __syncthreads();
                // xpose: Bs col lc holds gw = s0+lc-1 -> Xs col (lc==0 ? 129 : lc-1)
                #pragma unroll
                for (int it = 0; it < 3; ++it) {
                    int seg = it * 256 + t;
                    if (seg < 520) {
                        int lc  = seg >> 2;          // 0..129
                        int sub = seg & 3;           // 8-ci sub-chunk
                        int xc  = (lc == 0) ? 129 : (lc - 1);
                        u16x8 o;
                        #pragma unroll
                        for (int j = 0; j < 8; ++j)
                            o[j] = Xs[(sub * 8 + j) * 132 + xc];
                        int cg = cic * 4 + sub;      // global 16B chunk 0..15
                        *(u16x8*)(&Bs[lc * 128 + ((cg ^ (lc & 15)) * 8)]) = o;
                    }
                }
                __syncthreads();                     // before next pass reuses Xs
            }
        } else {
            // out-of-range row (h=0/kh=0 or h=255/kh=2): Bs = zeros
            u16x8 z = {0, 0, 0, 0, 0, 0, 0, 0};
            #pragma unroll
            for (int it = 0; it < 9; ++it) {
                int seg = it * 256 + t;
                if (seg < 2080) *(u16x8*)(&Bs[seg * 8]) = z;
            }
            __syncthreads();
        }

        // ---- 4 ci-quarters: stage A (ciq>0) + compute ----
        #pragma unroll 1
        for (int ciq = 0; ciq < 4; ++ciq) {
            if (ciq > 0) {
                __builtin_amdgcn_s_barrier();       // prev compute's LDS readers done
                stageA(kh, ciq);
            }
            asm volatile("s_waitcnt vmcnt(0)" ::: "memory");
            __builtin_amdgcn_s_barrier();
            __builtin_amdgcn_sched_barrier(0);

            // compute: one K32 step (R15-verified rotate path)
            {
                int ck = quad;                       // A local chunk 0..3
                int cb = ciq * 4 + quad;             // B global chunk 0..15

                bf16x8 af0[2], af1[2], af2[2];
                #pragma unroll
                for (int mi = 0; mi < 2; ++mi) {
                    int r  = wave * 32 + mi * 16 + l16;
                    int ro = r * 32 + (ck ^ ((r >> 1) & 3)) * 8;
                    af0[mi] = *(const bf16x8*)(&A0[ro]);
                    af1[mi] = *(const bf16x8*)(&A1[ro]);
                    af2[mi] = *(const bf16x8*)(&A2[ro]);
                }

                auto rdB = [&](int ni_) -> bf16x8 {
                    int lc = ni_ * 16 + l16;
                    if (lc > 129) lc = 129;          // halo lanes, values never selected
                    return *(const bf16x8*)(&Bs[lc * 128 + ((cb ^ (lc & 15)) * 8)]);
                };

                bf16x8 cur = rdB(0);
                #pragma unroll
                for (int ni = 0; ni < 8; ++ni) {
                    bf16x8 nxt = rdB(ni + 1);
                    bf16x8 r1c = rotf<ROR_P1>(cur), r1n = rotf<ROR_P1>(nxt);
                    bf16x8 s1  = (l16 == 15) ? r1n : r1c;
                    bf16x8 r2c = rotf<ROR_P2>(cur), r2n = rotf<ROR_P2>(nxt);
                    bf16x8 s2  = (l16 >= 14) ? r2n : r2c;

                    __builtin_amdgcn_s_setprio(1);
                    #pragma unroll
                    for (int mi = 0; mi < 2; ++mi)
                        acc[mi][ni] = __builtin_amdgcn_mfma_f32_16x16x32_bf16(
                            af0[mi], cur, acc[mi][ni], 0, 0, 0);
                    #pragma unroll
                    for (int mi = 0; mi < 2; ++mi)
                        acc[mi][ni] = __builtin_amdgcn_mfma_f32_16x16x32_bf16(
                            af1[mi], s1, acc[mi][ni], 0, 0, 0);
                    #pragma unroll
                    for (int mi = 0; mi < 2; ++mi)
                        acc[mi][ni] = __builtin_amdgcn_mfma_f32_16x16x32_bf16(
                            af2[mi], s2, acc[mi][ni], 0, 0, 0);
                    __builtin_amdgcn_s_setprio(0);
                    cur = nxt;
                }
            }
            __builtin_amdgcn_s_barrier();            // trailing: readers done
            __builtin_amdgcn_sched_barrier(0);
        }
        // trailing barrier of ciq=3 also protects Bs/Xs overwrite at next kh
    }

    // epilogue: C/D layout col(spatial)=lane&15, row(co)=quad*4+reg
    #pragma unroll
    for (int mi = 0; mi < 2; ++mi) {
        #pragma unroll
        for (int r = 0; r < 4; ++r) {
            int co = co0 + wave * 32 + mi * 16 + quad * 4 + r;
            float b = bias[co];
            float* orow = out + (size_t)co * (HH * WW) + h * WW + s0 + l16;
            #pragma unroll
            for (int ni = 0; ni < 8; ++ni)
                orow[ni * 16] = acc[mi][ni][r] + b;
        }
    }
}

extern "C" void kernel_launch(void* const* d_in, const int* in_sizes, int n_in,
                              void* d_out, int out_size, void* d_ws, size_t ws_size,
                              hipStream_t stream) {
    const float* x    = (const float*)d_in[0];   // [1,128,256,256]
    const float* w    = (const float*)d_in[1];   // [256,128,3,3]
    const float* bias = (const float*)d_in[2];   // [256]
    float* out        = (float*)d_out;           // [1,256,256,256]

    unsigned short* wr = (unsigned short*)d_ws;  // 9*256*128 bf16 = 589,824 B

    prep_kernel<<<dim3(128), dim3(256), 0, stream>>>(w, wr);
    conv_mfma_kernel<<<dim3(1024), dim3(256), 0, stream>>>(x, wr, bias, out);
}